// Round 5
// baseline (116.996 us; speedup 1.0000x reference)
//
#include <hip/hip_runtime.h>
#include <math.h>

#define BB 512
#define DD 16
#define NN 64
#define MM 32
#define RR 32
#define CC 10
#define BBLK 16          // b's per set (8 waves, 2 chains/wave/set)
#define SETS 2           // two 16-b sets per block sharing gf registers
#define ROWH 40          // halves per LDS row (80 B, 16B-aligned)
#define BREGH 1304       // halves per b region

typedef _Float16 v8h __attribute__((ext_vector_type(8)));
typedef float v4f __attribute__((ext_vector_type(4)));

union H8 { unsigned int u[4]; v8h h; _Float16 e[8]; };
union H4 { unsigned int u[2]; _Float16 e[4]; };

// ---------------------------------------------------------------------------
// Kernel 1 (unchanged): merged producers, all coalesced via LDS staging.
// ---------------------------------------------------------------------------
__global__ __launch_bounds__(256) void produce_kernel(
    const float* __restrict__ tensor, const float* __restrict__ W,
    const float* __restrict__ bias,   const float* __restrict__ G,
    _Float16* __restrict__ fh,        _Float16* __restrict__ gh) {
    __shared__ __align__(16) char smem[36864];
    const int t = threadIdx.x;
    if (blockIdx.x < 1024) {
        float* ten_s = (float*)smem;          // [8][64]
        float* W_s   = (float*)smem + 512;    // [64][32]
        const int bd0 = blockIdx.x * 8;
        if (t < 128)
            *(float4*)(ten_s + t * 4) = *(const float4*)(tensor + bd0 * NN + t * 4);
        *(float4*)(W_s + t * 4)        = *(const float4*)(W + t * 4);
        *(float4*)(W_s + 1024 + t * 4) = *(const float4*)(W + 1024 + t * 4);
        __syncthreads();
        const int m = t & 31, bd_l = t >> 5;
        float acc = bias[m];
#pragma unroll
        for (int n = 0; n < NN; ++n) acc += ten_s[bd_l * NN + n] * W_s[n * MM + m];
        fh[(bd0 + bd_l) * MM + m] = (_Float16)acc;
    } else {
        _Float16* lg = (_Float16*)smem;       // [di][m][j], m-stride 36 halves
        const int pb = blockIdx.x - 1024;     // 0..319
        const int c  = pb >> 5;
        const int d  = (pb >> 1) & 15;
        const int hf = pb & 1;
        const float* src = G + (size_t)(c * DD + d) * 32768 + hf * 16384;
#pragma unroll
        for (int k = 0; k < 16; ++k) {        // coalesced read of 64 KB slab-half
            const int f = (k * 256 + t) * 4;
            float4 v = *(const float4*)(src + f);
            const int di = f >> 10, m = (f >> 5) & 31, j = f & 31;
            H4 hv;
            hv.e[0] = (_Float16)v.x; hv.e[1] = (_Float16)v.y;
            hv.e[2] = (_Float16)v.z; hv.e[3] = (_Float16)v.w;
            *(uint2*)(lg + di * 1152 + m * 36 + j) = make_uint2(hv.u[0], hv.u[1]);
        }
        __syncthreads();
#pragma unroll
        for (int k = 0; k < 8; ++k) {         // coalesced 16B fragment writes
            const int idx = k * 256 + t;
            const int tl = idx >> 6, ln = idx & 63;
            const int di = tl >> 1, jh = tl & 1;
            const int q = ln >> 4, j4 = ln & 15;
            const int j = jh * 16 + j4;
            H8 o;
#pragma unroll
            for (int r = 0; r < 8; ++r)
                o.e[r] = lg[di * 1152 + (8 * q + r) * 36 + j];
            const size_t gi = ((size_t)(c * DD + d) * 64 + hf * 32 + tl) * 64 + ln;
            *(v8h*)(gh + gi * 8) = o.h;
        }
    }
}

// ---------------------------------------------------------------------------
// Kernel 2 (fused, gf-shared): per (c, b-block of 32): all 16 d's + trace.
// Transposed recurrence S_d = C_d^T * S_{d-1}; logits = diag-sum of S_15.
// The 32 b's are TWO 16-b sets sharing the per-wave gf fragments: gf is
// loaded once per (wave,d) and feeds both sets' phase-1 MFMAs -> gh L2
// traffic halves vs 16-b blocks (traffic = blocks/c × gh size; chain was
// L2-BW-bound at ~19 µs of L2 reads). Grid 160 = 1 block/CU, so
// __launch_bounds__(512,2) (256-VGPR budget) is free — no spill with both
// sets' av live (~180 regs peak). Each set has its own LDS region bank
// (83456 B static — gfx950 allows >64 KB static LDS), keeping 2 barriers/d.
// ---------------------------------------------------------------------------
__global__ __launch_bounds__(512, 2) void chain_kernel(
    const _Float16* __restrict__ feat_h,
    const _Float16* __restrict__ g_h,
    float* __restrict__ trout)         // [B][C] fp32 traces
{
    __shared__ __align__(16) _Float16 lds[SETS * BBLK * BREGH];  // 83456 B

    const int bid = blockIdx.x;        // 0..159
    const int xcd = bid & 7;
    const int idx = bid >> 3;          // 0..19
    int c, sub;
    if (idx < 16) { c = xcd; sub = idx; }
    else {
        const int e = idx - 16;        // 0..3
        c = 8 + (xcd >> 2);            // c8 on XCD 0-3, c9 on XCD 4-7
        sub = (xcd & 3) * 4 + e;       // 0..15
    }
    const int b0 = sub * (SETS * BBLK);   // 32 b's per block
    const int t    = threadIdx.x;
    const int w    = t >> 6;           // wave 0..7
    const int lane = t & 63;
    const int q    = lane >> 4;
    const int j4   = lane & 15;

    const size_t gc = (size_t)c * DD * 32768;

    // prefetch d=0 fragments (A-frags for both sets; shared G frags)
    v8h afh[2];
#pragma unroll
    for (int bs = 0; bs < 2; ++bs)
        afh[bs] = *(const v8h*)(feat_h + (size_t)(b0 + 16 * bs + j4) * (DD * MM) + q * 8);
    v8h gf[8];
#pragma unroll
    for (int u = 0; u < 8; ++u)
        gf[u] = *(const v8h*)(g_h + gc + ((size_t)(w * 8 + u) * 64 + lane) * 8);

    v8h sb[4][2];                      // [chain ch][vt]  state B-frags

    for (int d = 0; d < DD; ++d) {
        __syncthreads();   // WAR: previous phase-2 LDS use done
        // ---- phase 1: 16 MFMAs (2 sets x 8), gf shared -------------------
        v4f av[2][8];
#pragma unroll
        for (int bs = 0; bs < 2; ++bs)
#pragma unroll
            for (int u = 0; u < 8; ++u) {
                v4f z = {0.f, 0.f, 0.f, 0.f};
                av[bs][u] = __builtin_amdgcn_mfma_f32_16x16x32_f16(
                    afh[bs], gf[u], z, 0, 0, 0);
            }
        if (d < DD - 1) {              // prefetch d+1 (overlaps stores + phase 2)
#pragma unroll
            for (int bs = 0; bs < 2; ++bs)
                afh[bs] = *(const v8h*)(feat_h +
                    (size_t)(b0 + 16 * bs + j4) * (DD * MM) + (d + 1) * MM + q * 8);
            const size_t gb = gc + (size_t)(d + 1) * 32768;
#pragma unroll
            for (int u = 0; u < 8; ++u)
                gf[u] = *(const v8h*)(g_h + gb + ((size_t)(w * 8 + u) * 64 + lane) * 8);
        }
        // store cores: set bs region, L[b=4q+reg][j][i], i = 4w+ii contiguous
#pragma unroll
        for (int bs = 0; bs < 2; ++bs)
#pragma unroll
            for (int jh = 0; jh < 2; ++jh)
#pragma unroll
                for (int reg = 0; reg < 4; ++reg) {
                    H4 hv;
                    hv.e[0] = (_Float16)av[bs][0 + jh][reg];
                    hv.e[1] = (_Float16)av[bs][2 + jh][reg];
                    hv.e[2] = (_Float16)av[bs][4 + jh][reg];
                    hv.e[3] = (_Float16)av[bs][6 + jh][reg];
                    *(uint2*)(&lds[(bs * BBLK + 4 * q + reg) * BREGH +
                                   (16 * jh + j4) * ROWH + 4 * w]) =
                        make_uint2(hv.u[0], hv.u[1]);
                }
        __syncthreads();   // cores ready
        // ---- phase 2: wave w advances 4 chains (2 per set) ---------------
#pragma unroll
        for (int ch = 0; ch < 4; ++ch) {
            const int bs = ch >> 1;
            const int bl = 2 * w + (ch & 1);
            _Float16* base = lds + (bs * BBLK + bl) * BREGH;
            if (d == 0) {
                // init S = C_0^T as B-frag: sb[vt][k=8q+r][col=j4]
#pragma unroll
                for (int vt = 0; vt < 2; ++vt) {
                    H8 x;
#pragma unroll
                    for (int r = 0; r < 8; ++r)
                        x.e[r] = base[(8 * q + r) * ROWH + 16 * vt + j4];
                    sb[ch][vt] = x.h;
                }
            } else {
                // A = C_d^T frags (b128 reads)
                v8h af2[2];
#pragma unroll
                for (int jt = 0; jt < 2; ++jt)
                    af2[jt] = *(const v8h*)(base + (16 * jt + j4) * ROWH + 8 * q);
                if (d == DD - 1) {
                    // only the two diagonal tiles matter for the trace
                    v4f z0 = {0.f, 0.f, 0.f, 0.f};
                    v4f a0 = __builtin_amdgcn_mfma_f32_16x16x32_f16(
                        af2[0], sb[ch][0], z0, 0, 0, 0);
                    v4f z1 = {0.f, 0.f, 0.f, 0.f};
                    v4f a1 = __builtin_amdgcn_mfma_f32_16x16x32_f16(
                        af2[1], sb[ch][1], z1, 0, 0, 0);
                    float ts = 0.f;
#pragma unroll
                    for (int reg = 0; reg < 4; ++reg)
                        if (j4 == 4 * q + reg) ts = a0[reg] + a1[reg];
#pragma unroll
                    for (int off = 32; off > 0; off >>= 1)
                        ts += __shfl_xor(ts, off);
                    if (lane == 0)
                        trout[(size_t)(b0 + 16 * bs + bl) * CC + c] = ts;
                } else {
                    v4f acc[2][2];
#pragma unroll
                    for (int jt = 0; jt < 2; ++jt)
#pragma unroll
                        for (int vt = 0; vt < 2; ++vt) {
                            v4f z = {0.f, 0.f, 0.f, 0.f};
                            acc[jt][vt] = __builtin_amdgcn_mfma_f32_16x16x32_f16(
                                af2[jt], sb[ch][vt], z, 0, 0, 0);
                        }
                    // write S_new packed: M[v=16vt+j4][j=16jt+4q+reg] (b64)
#pragma unroll
                    for (int jt = 0; jt < 2; ++jt)
#pragma unroll
                        for (int vt = 0; vt < 2; ++vt) {
                            H4 hv;
                            hv.e[0] = (_Float16)acc[jt][vt][0];
                            hv.e[1] = (_Float16)acc[jt][vt][1];
                            hv.e[2] = (_Float16)acc[jt][vt][2];
                            hv.e[3] = (_Float16)acc[jt][vt][3];
                            *(uint2*)(base + (16 * vt + j4) * ROWH + 16 * jt + 4 * q) =
                                make_uint2(hv.u[0], hv.u[1]);
                        }
                    __builtin_amdgcn_sched_barrier(0);
                    // re-read state as B-frags (b128)
#pragma unroll
                    for (int vt = 0; vt < 2; ++vt)
                        sb[ch][vt] = *(const v8h*)(base + (16 * vt + j4) * ROWH + 8 * q);
                }
            }
        }
    }
}

// ---------------------------------------------------------------------------
// Kernel 3: tiny log-softmax over the [B][C] trace buffer (20 KB).
// ---------------------------------------------------------------------------
__global__ __launch_bounds__(256) void lsm_kernel(
    const float* __restrict__ tr, float* __restrict__ out) {
    const int b = blockIdx.x * 256 + threadIdx.x;   // 2 blocks x 256 = 512
    float v[CC];
    float mx = -1e30f;
#pragma unroll
    for (int c = 0; c < CC; ++c) {
        v[c] = tr[b * CC + c];
        mx = fmaxf(mx, v[c]);
    }
    float ssum = 0.f;
#pragma unroll
    for (int c = 0; c < CC; ++c) ssum += expf(v[c] - mx);
    const float ls = logf(ssum);
#pragma unroll
    for (int c = 0; c < CC; ++c) out[b * CC + c] = v[c] - mx - ls;
}

// ---------------------------------------------------------------------------
extern "C" void kernel_launch(void* const* d_in, const int* in_sizes, int n_in,
                              void* d_out, int out_size, void* d_ws, size_t ws_size,
                              hipStream_t stream) {
    const float* tensor = (const float*)d_in[0];
    const float* W      = (const float*)d_in[1];
    const float* bias   = (const float*)d_in[2];
    const float* G      = (const float*)d_in[3];
    float* out = (float*)d_out;

    const size_t FEAT = (size_t)BB * DD * MM;          // 262144 halves
    const size_t GPK  = (size_t)CC * DD * 64 * 64 * 8; // 5242880 halves
    _Float16* fh = (_Float16*)d_ws;
    _Float16* gh = fh + FEAT;
    float* trbuf = (float*)(gh + GPK);                 // 512*10 fp32 (20 KB)

    produce_kernel<<<1024 + 320, 256, 0, stream>>>(tensor, W, bias, G, fh, gh);
    chain_kernel<<<CC * (BB / (SETS * BBLK)), 512, 0, stream>>>(fh, gh, trbuf);
    lsm_kernel<<<BB / 256, 256, 0, stream>>>(trbuf, out);
}